// Round 1
// baseline (1469.615 us; speedup 1.0000x reference)
//
#include <hip/hip_runtime.h>
#include <math.h>

constexpr int C_ = 768;
constexpr int S_ = 2048;
constexpr int H_ = 12;
constexpr int M_ = 100;

__device__ __forceinline__ float sigmoidf_(float x) {
    return 1.0f / (1.0f + __expf(-x));
}

// ---------------------------------------------------------------------------
// Generic fp32 tiled GEMM: C[M,N] = A[M,K] @ W[K,N] (+bias, + optional epilogue)
// BM=BN=64, BK=16, 256 threads, 4x4 per thread.
// CONCAT: A is [a | a1] concatenated along K (each lda=768).
// EPI==1: alpha = sigmoid(acc+bias); C = alpha*ea + (1-alpha)*ea1  (fuse gate)
// ---------------------------------------------------------------------------
template<bool CONCAT, int EPI>
__global__ __launch_bounds__(256)
void gemm64(const float* __restrict__ A, const float* __restrict__ A2,
            const float* __restrict__ W, const float* __restrict__ bias,
            float* __restrict__ Cout, int M, int N, int K, int lda, int ldc,
            const float* __restrict__ ea, const float* __restrict__ ea1)
{
    constexpr int BM = 64, BN = 64, BK = 16;
    __shared__ float As[BK][BM + 4];   // transposed A tile, pad->68 (16B aligned rows)
    __shared__ float Ws[BK][BN];

    const int tid = threadIdx.x;
    const int tx = tid & 15, ty = tid >> 4;
    const int row0 = blockIdx.y * BM, col0 = blockIdx.x * BN;
    const int ar = tid >> 2, ac4 = (tid & 3) << 2;   // A-load: row, 4-col group

    float acc[4][4] = {};

    for (int k0 = 0; k0 < K; k0 += BK) {
        // global loads (issued before barrier for latency hiding)
        float4 av = make_float4(0.f, 0.f, 0.f, 0.f);
        const int grow = row0 + ar;
        const int gk = k0 + ac4;
        if (grow < M) {
            if (CONCAT) {
                const float* src = (gk < 768) ? (A  + (size_t)grow * 768 + gk)
                                              : (A2 + (size_t)grow * 768 + (gk - 768));
                av = *(const float4*)src;
            } else {
                av = *(const float4*)(A + (size_t)grow * lda + gk);
            }
        }
        const float4 wv = *(const float4*)(W + (size_t)(k0 + ty) * N + col0 + (tx << 2));

        __syncthreads();   // previous iteration's LDS reads complete
        As[ac4 + 0][ar] = av.x;
        As[ac4 + 1][ar] = av.y;
        As[ac4 + 2][ar] = av.z;
        As[ac4 + 3][ar] = av.w;
        *(float4*)&Ws[ty][tx << 2] = wv;
        __syncthreads();

        #pragma unroll
        for (int kk = 0; kk < BK; ++kk) {
            const float4 a4 = *(const float4*)&As[kk][ty << 2];
            const float4 b4 = *(const float4*)&Ws[kk][tx << 2];
            const float arr[4] = {a4.x, a4.y, a4.z, a4.w};
            const float brr[4] = {b4.x, b4.y, b4.z, b4.w};
            #pragma unroll
            for (int i = 0; i < 4; ++i)
                #pragma unroll
                for (int j = 0; j < 4; ++j)
                    acc[i][j] = fmaf(arr[i], brr[j], acc[i][j]);
        }
    }

    const int crow0 = row0 + (ty << 2);
    const int ccol = col0 + (tx << 2);
    const float4 bv = *(const float4*)(bias + ccol);
    #pragma unroll
    for (int r = 0; r < 4; ++r) {
        const int crow = crow0 + r;
        if (crow >= M) continue;
        float4 o;
        o.x = acc[r][0] + bv.x;
        o.y = acc[r][1] + bv.y;
        o.z = acc[r][2] + bv.z;
        o.w = acc[r][3] + bv.w;
        if (EPI == 1) {
            const float4 av  = *(const float4*)(ea  + (size_t)crow * 768 + ccol);
            const float4 a1v = *(const float4*)(ea1 + (size_t)crow * 768 + ccol);
            float al;
            al = sigmoidf_(o.x); o.x = al * av.x + (1.f - al) * a1v.x;
            al = sigmoidf_(o.y); o.y = al * av.y + (1.f - al) * a1v.y;
            al = sigmoidf_(o.z); o.z = al * av.z + (1.f - al) * a1v.z;
            al = sigmoidf_(o.w); o.w = al * av.w + (1.f - al) * a1v.w;
        }
        *(float4*)(Cout + (size_t)crow * ldc + ccol) = o;
    }
}

// ---------------------------------------------------------------------------
// Flash self-attention, fp32, no 1/sqrt(d) scaling (matches reference).
// One block per (64-row Q tile, b, h). 256 threads, 4x4 per thread.
// qkv layout: [B*S][2304], q at col h*64, k at 768+h*64, v at 1536+h*64.
// ---------------------------------------------------------------------------
__global__ __launch_bounds__(256)
void attn_self(const float* __restrict__ qkv, float* __restrict__ a_out)
{
    __shared__ float Qt[64][68];   // [d][qrow]
    __shared__ float Kt[64][68];   // [d][krow]
    __shared__ float Vs[64][68];   // [krow][d]
    __shared__ float Ps[64][68];   // [qrow][krow]

    const int tid = threadIdx.x;
    const int tx = tid & 15, ty = tid >> 4;
    const int q0 = blockIdx.x * 64;
    const int b = blockIdx.y / H_;
    const int h = blockIdx.y % H_;
    const float* qb = qkv + (size_t)(b * S_) * 2304 + h * 64;
    const float* kb = qb + 768;
    const float* vb = qb + 1536;

    #pragma unroll
    for (int j = 0; j < 4; ++j) {
        const int fid = j * 256 + tid;
        const int r = fid >> 4, c4 = (fid & 15) << 2;
        const float4 q4 = *(const float4*)(qb + (size_t)(q0 + r) * 2304 + c4);
        Qt[c4 + 0][r] = q4.x; Qt[c4 + 1][r] = q4.y;
        Qt[c4 + 2][r] = q4.z; Qt[c4 + 3][r] = q4.w;
    }

    float mrow[4], lrow[4], O[4][4];
    #pragma unroll
    for (int r = 0; r < 4; ++r) {
        mrow[r] = -3.0e38f; lrow[r] = 0.f;
        #pragma unroll
        for (int c = 0; c < 4; ++c) O[r][c] = 0.f;
    }
    __syncthreads();

    for (int t = 0; t < S_ / 64; ++t) {
        const int k0 = t * 64;
        float4 kq[4], vq[4];
        #pragma unroll
        for (int j = 0; j < 4; ++j) {
            const int fid = j * 256 + tid;
            const int r = fid >> 4, c4 = (fid & 15) << 2;
            kq[j] = *(const float4*)(kb + (size_t)(k0 + r) * 2304 + c4);
            vq[j] = *(const float4*)(vb + (size_t)(k0 + r) * 2304 + c4);
        }
        __syncthreads();   // previous iteration done reading Kt/Vs/Ps
        #pragma unroll
        for (int j = 0; j < 4; ++j) {
            const int fid = j * 256 + tid;
            const int r = fid >> 4, c4 = (fid & 15) << 2;
            Kt[c4 + 0][r] = kq[j].x; Kt[c4 + 1][r] = kq[j].y;
            Kt[c4 + 2][r] = kq[j].z; Kt[c4 + 3][r] = kq[j].w;
            *(float4*)&Vs[r][c4] = vq[j];
        }
        __syncthreads();

        // S = Q K^T  (rows ty*4.., cols tx*4..)
        float Sv[4][4] = {};
        #pragma unroll
        for (int d = 0; d < 64; ++d) {
            const float4 qa = *(const float4*)&Qt[d][ty << 2];
            const float4 ka = *(const float4*)&Kt[d][tx << 2];
            const float qr[4] = {qa.x, qa.y, qa.z, qa.w};
            const float kr[4] = {ka.x, ka.y, ka.z, ka.w};
            #pragma unroll
            for (int r = 0; r < 4; ++r)
                #pragma unroll
                for (int c = 0; c < 4; ++c)
                    Sv[r][c] = fmaf(qr[r], kr[c], Sv[r][c]);
        }

        // online softmax update (row groups = 16 consecutive lanes, shfl_xor)
        #pragma unroll
        for (int r = 0; r < 4; ++r) {
            float rm = fmaxf(fmaxf(Sv[r][0], Sv[r][1]), fmaxf(Sv[r][2], Sv[r][3]));
            rm = fmaxf(rm, __shfl_xor(rm, 1, 64));
            rm = fmaxf(rm, __shfl_xor(rm, 2, 64));
            rm = fmaxf(rm, __shfl_xor(rm, 4, 64));
            rm = fmaxf(rm, __shfl_xor(rm, 8, 64));
            const float mn = fmaxf(mrow[r], rm);
            const float sc = __expf(mrow[r] - mn);
            mrow[r] = mn;
            float s = 0.f;
            #pragma unroll
            for (int c = 0; c < 4; ++c) {
                const float p = __expf(Sv[r][c] - mn);
                Ps[(ty << 2) + r][(tx << 2) + c] = p;
                s += p;
            }
            s += __shfl_xor(s, 1, 64);
            s += __shfl_xor(s, 2, 64);
            s += __shfl_xor(s, 4, 64);
            s += __shfl_xor(s, 8, 64);
            lrow[r] = lrow[r] * sc + s;
            #pragma unroll
            for (int c = 0; c < 4; ++c) O[r][c] *= sc;
        }
        __syncthreads();   // Ps visible

        // O += P @ V
        #pragma unroll
        for (int kk = 0; kk < 64; ++kk) {
            const float4 va = *(const float4*)&Vs[kk][tx << 2];
            const float vr[4] = {va.x, va.y, va.z, va.w};
            float pa[4];
            #pragma unroll
            for (int r = 0; r < 4; ++r) pa[r] = Ps[(ty << 2) + r][kk];
            #pragma unroll
            for (int r = 0; r < 4; ++r)
                #pragma unroll
                for (int c = 0; c < 4; ++c)
                    O[r][c] = fmaf(pa[r], vr[c], O[r][c]);
        }
    }

    #pragma unroll
    for (int r = 0; r < 4; ++r) {
        const float inv = 1.0f / lrow[r];
        const int row = q0 + (ty << 2) + r;
        const float4 o = make_float4(O[r][0] * inv, O[r][1] * inv,
                                     O[r][2] * inv, O[r][3] * inv);
        *(float4*)(a_out + (size_t)(b * S_ + row) * 768 + h * 64 + (tx << 2)) = o;
    }
}

// ---------------------------------------------------------------------------
// Memory attention: q [2048x64] vs mk/mv [100x64] per (b,h). Single pass.
// mkv layout: [100][1536], mk at col h*64, mv at col 768+h*64.
// ---------------------------------------------------------------------------
__global__ __launch_bounds__(256)
void attn_mem(const float* __restrict__ qkv, const float* __restrict__ mkv,
              float* __restrict__ a1_out)
{
    __shared__ float Qt[64][68];     // [d][qrow]
    __shared__ float Kmt[64][112];   // [d][slot], cols 100..111 zeroed
    __shared__ float Vm[100][68];    // [slot][d]
    __shared__ float Psm[64][104];   // [qrow][slot]

    const int tid = threadIdx.x;
    const int tx = tid & 15, ty = tid >> 4;
    const int q0 = blockIdx.x * 64;
    const int b = blockIdx.y / H_;
    const int h = blockIdx.y % H_;
    const float* qb = qkv + (size_t)(b * S_) * 2304 + h * 64;

    #pragma unroll
    for (int j = 0; j < 4; ++j) {
        const int fid = j * 256 + tid;
        const int r = fid >> 4, c4 = (fid & 15) << 2;
        const float4 q4 = *(const float4*)(qb + (size_t)(q0 + r) * 2304 + c4);
        Qt[c4 + 0][r] = q4.x; Qt[c4 + 1][r] = q4.y;
        Qt[c4 + 2][r] = q4.z; Qt[c4 + 3][r] = q4.w;
    }
    // mk (transposed) and mv: 100 rows x 16 float4
    #pragma unroll
    for (int j = 0; j < 7; ++j) {
        const int fid = j * 256 + tid;
        if (fid < 1600) {
            const int r = fid >> 4, c4 = (fid & 15) << 2;
            const float4 k4 = *(const float4*)(mkv + (size_t)r * 1536 + h * 64 + c4);
            const float4 v4 = *(const float4*)(mkv + (size_t)r * 1536 + 768 + h * 64 + c4);
            Kmt[c4 + 0][r] = k4.x; Kmt[c4 + 1][r] = k4.y;
            Kmt[c4 + 2][r] = k4.z; Kmt[c4 + 3][r] = k4.w;
            *(float4*)&Vm[r][c4] = v4;
        }
    }
    // zero pad slots 100..111 so unguarded score FMAs read 0 (masked later)
    for (int idx = tid; idx < 64 * 12; idx += 256) {
        Kmt[idx / 12][100 + idx % 12] = 0.f;
    }
    __syncthreads();

    // scores: rows ty*4..+3, cols tx + 16*c (c<7)
    float Sm[4][7] = {};
    #pragma unroll
    for (int d = 0; d < 64; ++d) {
        const float4 qa = *(const float4*)&Qt[d][ty << 2];
        const float qr[4] = {qa.x, qa.y, qa.z, qa.w};
        #pragma unroll
        for (int c = 0; c < 7; ++c) {
            const float kv = Kmt[d][tx + 16 * c];
            #pragma unroll
            for (int r = 0; r < 4; ++r)
                Sm[r][c] = fmaf(qr[r], kv, Sm[r][c]);
        }
    }

    float l[4];
    #pragma unroll
    for (int r = 0; r < 4; ++r) {
        float rm = -3.0e38f;
        #pragma unroll
        for (int c = 0; c < 7; ++c)
            if (tx + 16 * c < 100) rm = fmaxf(rm, Sm[r][c]);
        rm = fmaxf(rm, __shfl_xor(rm, 1, 64));
        rm = fmaxf(rm, __shfl_xor(rm, 2, 64));
        rm = fmaxf(rm, __shfl_xor(rm, 4, 64));
        rm = fmaxf(rm, __shfl_xor(rm, 8, 64));
        float s = 0.f;
        #pragma unroll
        for (int c = 0; c < 7; ++c) {
            const int jcol = tx + 16 * c;
            if (jcol < 100) {
                const float p = __expf(Sm[r][c] - rm);
                Psm[(ty << 2) + r][jcol] = p;
                s += p;
            }
        }
        s += __shfl_xor(s, 1, 64);
        s += __shfl_xor(s, 2, 64);
        s += __shfl_xor(s, 4, 64);
        s += __shfl_xor(s, 8, 64);
        l[r] = s;
    }
    __syncthreads();

    float acc[4][4] = {};
    for (int k = 0; k < 100; ++k) {
        const float4 va = *(const float4*)&Vm[k][tx << 2];
        const float vr[4] = {va.x, va.y, va.z, va.w};
        float pa[4];
        #pragma unroll
        for (int r = 0; r < 4; ++r) pa[r] = Psm[(ty << 2) + r][k];
        #pragma unroll
        for (int r = 0; r < 4; ++r)
            #pragma unroll
            for (int c = 0; c < 4; ++c)
                acc[r][c] = fmaf(pa[r], vr[c], acc[r][c]);
    }

    #pragma unroll
    for (int r = 0; r < 4; ++r) {
        const float inv = 1.0f / l[r];
        const int row = q0 + (ty << 2) + r;
        const float4 o = make_float4(acc[r][0] * inv, acc[r][1] * inv,
                                     acc[r][2] * inv, acc[r][3] * inv);
        *(float4*)(a1_out + (size_t)(b * S_ + row) * 768 + h * 64 + (tx << 2)) = o;
    }
}

// ---------------------------------------------------------------------------
extern "C" void kernel_launch(void* const* d_in, const int* in_sizes, int n_in,
                              void* d_out, int out_size, void* d_ws, size_t ws_size,
                              hipStream_t stream)
{
    const float* x       = (const float*)d_in[0];
    const float* w_attn  = (const float*)d_in[1];
    const float* b_attn  = (const float*)d_in[2];
    const float* w_proj  = (const float*)d_in[3];
    const float* b_proj  = (const float*)d_in[4];
    const float* w_mem   = (const float*)d_in[5];
    const float* b_mem   = (const float*)d_in[6];
    const float* w_alpha = (const float*)d_in[7];
    const float* b_alpha = (const float*)d_in[8];
    const float* memf    = (const float*)d_in[9];
    float* out = (float*)d_out;

    const int B = in_sizes[0] / (S_ * C_);   // 2
    const int BS = B * S_;                   // 4096

    float* ws    = (float*)d_ws;
    float* qkv   = ws;                               // [BS][2304]
    float* mkv   = qkv + (size_t)BS * 2304;          // [100][1536]
    float* a     = mkv + (size_t)M_ * 1536;          // [BS][768]
    float* a1    = a   + (size_t)BS * C_;            // [BS][768]
    float* fused = a1  + (size_t)BS * C_;            // [BS][768]

    const dim3 blk(256);

    // qkv = x @ w_attn + b_attn
    gemm64<false, 0><<<dim3(2304 / 64, BS / 64), blk, 0, stream>>>(
        x, nullptr, w_attn, b_attn, qkv, BS, 2304, 768, 768, 2304, nullptr, nullptr);

    // mkv = mem @ w_mem + b_mem   (broadcast batch: compute once)
    gemm64<false, 0><<<dim3(1536 / 64, 2), blk, 0, stream>>>(
        memf, nullptr, w_mem, b_mem, mkv, M_, 1536, 768, 768, 1536, nullptr, nullptr);

    // a = self-attention(q,k,v)
    attn_self<<<dim3(S_ / 64, B * H_), blk, 0, stream>>>(qkv, a);

    // a1 = memory-attention(q, mk, mv)
    attn_mem<<<dim3(S_ / 64, B * H_), blk, 0, stream>>>(qkv, mkv, a1);

    // fused = sigmoid([a|a1] @ w_alpha + b_alpha) * a + (1-sigmoid) * a1
    gemm64<true, 1><<<dim3(768 / 64, BS / 64), blk, 0, stream>>>(
        a, a1, w_alpha, b_alpha, fused, BS, 768, 1536, 768, 768, a, a1);

    // out = fused @ w_proj + b_proj
    gemm64<false, 0><<<dim3(768 / 64, BS / 64), blk, 0, stream>>>(
        fused, nullptr, w_proj, b_proj, out, BS, 768, 768, 768, 768, nullptr, nullptr);
}

// Round 7
// 757.188 us; speedup vs baseline: 1.9409x; 1.9409x over previous
//
#include <hip/hip_runtime.h>
#include <math.h>

constexpr int C_ = 768;
constexpr int S_ = 2048;
constexpr int H_ = 12;
constexpr int M_ = 100;

typedef unsigned short ushortT;
typedef unsigned long long ull;
typedef short s8v __attribute__((ext_vector_type(8)));
typedef float f32x16 __attribute__((ext_vector_type(16)));
typedef unsigned short u16x4 __attribute__((ext_vector_type(4)));

__device__ __forceinline__ float sigmoidf_(float x) {
    return 1.0f / (1.0f + __expf(-x));
}
__device__ __forceinline__ ushortT f2bf(float f) {
    unsigned int u = __float_as_uint(f);
    u += 0x7FFFu + ((u >> 16) & 1u);
    return (ushortT)(u >> 16);
}
__device__ __forceinline__ float bf2f(ushortT h) {
    return __uint_as_float(((unsigned int)h) << 16);
}

// ---------------------------------------------------------------------------
// fp32 tiled GEMM — used only for the tiny mkv GEMM (100x1536, K=768).
// ---------------------------------------------------------------------------
__global__ __launch_bounds__(256)
void gemm64(const float* __restrict__ A, const float* __restrict__ W,
            const float* __restrict__ bias, float* __restrict__ Cout,
            int M, int N, int K)
{
    constexpr int BM = 64, BN = 64, BK = 16;
    __shared__ float As[BK][BM + 4];
    __shared__ float Ws[BK][BN];

    const int tid = threadIdx.x;
    const int tx = tid & 15, ty = tid >> 4;
    const int row0 = blockIdx.y * BM, col0 = blockIdx.x * BN;
    const int ar = tid >> 2, ac4 = (tid & 3) << 2;

    float acc[4][4] = {};

    for (int k0 = 0; k0 < K; k0 += BK) {
        float4 av = make_float4(0.f, 0.f, 0.f, 0.f);
        const int grow = row0 + ar;
        const int gk = k0 + ac4;
        if (grow < M) av = *(const float4*)(A + (size_t)grow * K + gk);
        const float4 wv = *(const float4*)(W + (size_t)(k0 + ty) * N + col0 + (tx << 2));

        __syncthreads();
        As[ac4 + 0][ar] = av.x;
        As[ac4 + 1][ar] = av.y;
        As[ac4 + 2][ar] = av.z;
        As[ac4 + 3][ar] = av.w;
        *(float4*)&Ws[ty][tx << 2] = wv;
        __syncthreads();

        #pragma unroll
        for (int kk = 0; kk < BK; ++kk) {
            const float4 a4 = *(const float4*)&As[kk][ty << 2];
            const float4 b4 = *(const float4*)&Ws[kk][tx << 2];
            const float arr[4] = {a4.x, a4.y, a4.z, a4.w};
            const float brr[4] = {b4.x, b4.y, b4.z, b4.w};
            #pragma unroll
            for (int i = 0; i < 4; ++i)
                #pragma unroll
                for (int j = 0; j < 4; ++j)
                    acc[i][j] = fmaf(arr[i], brr[j], acc[i][j]);
        }
    }

    const int crow0 = row0 + (ty << 2);
    const int ccol = col0 + (tx << 2);
    const float4 bv = *(const float4*)(bias + ccol);
    #pragma unroll
    for (int r = 0; r < 4; ++r) {
        const int crow = crow0 + r;
        if (crow >= M) continue;
        float4 o;
        o.x = acc[r][0] + bv.x;
        o.y = acc[r][1] + bv.y;
        o.z = acc[r][2] + bv.z;
        o.w = acc[r][3] + bv.w;
        *(float4*)(Cout + (size_t)crow * N + ccol) = o;
    }
}

// ---------------------------------------------------------------------------
// Weight prep: W [K][N] fp32 -> WT hi/lo bf16 [N][K] (transpose + split).
// ---------------------------------------------------------------------------
__global__ __launch_bounds__(256)
void prep_wT(const float* __restrict__ W, ushortT* __restrict__ Thi,
             ushortT* __restrict__ Tlo, int K, int N)
{
    __shared__ float Ts[64][65];
    const int tid = threadIdx.x;
    const int n0 = blockIdx.x * 64, k0 = blockIdx.y * 64;
    #pragma unroll
    for (int j = 0; j < 4; ++j) {
        const int row = (tid >> 4) + j * 16;
        const int c4 = (tid & 15) << 2;
        *(float4*)&Ts[row][c4] = *(const float4*)(W + (size_t)(k0 + row) * N + n0 + c4);
    }
    __syncthreads();
    const int nr = tid >> 2, ks = (tid & 3) << 4;
    u16x4 hv[4], lv[4];
    #pragma unroll
    for (int t = 0; t < 16; ++t) {
        const float f = Ts[ks + t][nr];
        const ushortT hi = f2bf(f);
        hv[t >> 2][t & 3] = hi;
        lv[t >> 2][t & 3] = f2bf(f - bf2f(hi));
    }
    ushortT* ph = Thi + (size_t)(n0 + nr) * K + k0 + ks;
    ushortT* pl = Tlo + (size_t)(n0 + nr) * K + k0 + ks;
    #pragma unroll
    for (int q = 0; q < 4; ++q) {
        *(u16x4*)(ph + q * 4) = hv[q];
        *(u16x4*)(pl + q * 4) = lv[q];
    }
}

// ---------------------------------------------------------------------------
// Elementwise split: X fp32 -> hi/lo bf16 (same layout).
// ---------------------------------------------------------------------------
__global__ __launch_bounds__(256)
void prep_split(const float* __restrict__ X, ushortT* __restrict__ Xhi,
                ushortT* __restrict__ Xlo, int n4)
{
    const int i = blockIdx.x * 256 + threadIdx.x;
    if (i >= n4) return;
    const float4 v = ((const float4*)X)[i];
    const float a[4] = {v.x, v.y, v.z, v.w};
    u16x4 h, l;
    #pragma unroll
    for (int e = 0; e < 4; ++e) {
        const ushortT hi = f2bf(a[e]);
        h[e] = hi;
        l[e] = f2bf(a[e] - bf2f(hi));
    }
    ((u16x4*)Xhi)[i] = h;
    ((u16x4*)Xlo)[i] = l;
}

// ---------------------------------------------------------------------------
// MFMA helpers (32x32x16 bf16). Fragment reads from [.][68]-padded LDS rows.
// ---------------------------------------------------------------------------
__device__ __forceinline__ s8v ldfrag(const ushortT* p) {
    union { s8v v; ull q[2]; } u;
    u.q[0] = *(const ull*)(p);
    u.q[1] = *(const ull*)(p + 8);
    return u.v;
}
__device__ __forceinline__ void get64(uint4* v, const ushortT* s) {
    v[0] = *(const uint4*)(s);
    v[1] = *(const uint4*)(s + 8);
    v[2] = *(const uint4*)(s + 16);
    v[3] = *(const uint4*)(s + 24);
}
__device__ __forceinline__ void put64(ushortT* dst, const uint4* v) {
    uint2* d = (uint2*)dst;
    d[0] = make_uint2(v[0].x, v[0].y); d[1] = make_uint2(v[0].z, v[0].w);
    d[2] = make_uint2(v[1].x, v[1].y); d[3] = make_uint2(v[1].z, v[1].w);
    d[4] = make_uint2(v[2].x, v[2].y); d[5] = make_uint2(v[2].z, v[2].w);
    d[6] = make_uint2(v[3].x, v[3].y); d[7] = make_uint2(v[3].z, v[3].w);
}
#define MFMA32(a, b, c) __builtin_amdgcn_mfma_f32_32x32x16_bf16(a, b, c, 0, 0, 0)

// ---------------------------------------------------------------------------
// Split-bf16 MFMA GEMM: C[M,N] = (Ahi+Alo)[M,K] @ (WThi+WTlo)^T + bias.
// 3-term (drops lo*lo). BM=BN=128, BK=64, 256 thr = 4 waves, each 64x64
// (four 32x32 acc tiles). A and WT both row-major with K contiguous.
// EPI 0: Cout fp32. EPI 1: gate — alpha=sigmoid(o); read a/a1 from cat
// hi/lo (a at [m][n], a1 at [m][768+n]); write fused hi/lo bf16.
// ---------------------------------------------------------------------------
template<int EPI>
__global__ __launch_bounds__(256)
void gemm_mfma(const ushortT* __restrict__ Ahi, const ushortT* __restrict__ Alo,
               const ushortT* __restrict__ WThi, const ushortT* __restrict__ WTlo,
               const float* __restrict__ bias, float* __restrict__ Cout,
               const ushortT* __restrict__ cat_hi, const ushortT* __restrict__ cat_lo,
               ushortT* __restrict__ Fhi, ushortT* __restrict__ Flo,
               int M, int N, int K)
{
    __shared__ ushortT AhL[128][68];
    __shared__ ushortT AlL[128][68];
    __shared__ ushortT WhL[128][68];
    __shared__ ushortT WlL[128][68];

    const int tid = threadIdx.x, lane = tid & 63, wv = tid >> 6;
    const int l5 = lane & 31, g2 = lane >> 5;
    const int wm = wv & 1, wn = wv >> 1;
    const int m0 = blockIdx.y * 128, n0 = blockIdx.x * 128;
    const int sr = tid >> 1, sh = (tid & 1) << 5;

    f32x16 acc[2][2];
    #pragma unroll
    for (int i = 0; i < 16; ++i) {
        acc[0][0][i] = 0.f; acc[0][1][i] = 0.f;
        acc[1][0][i] = 0.f; acc[1][1][i] = 0.f;
    }

    const ushortT* pAh = Ahi + (size_t)(m0 + sr) * K + sh;
    const ushortT* pAl = Alo + (size_t)(m0 + sr) * K + sh;
    const ushortT* pWh = WThi + (size_t)(n0 + sr) * K + sh;
    const ushortT* pWl = WTlo + (size_t)(n0 + sr) * K + sh;

    for (int k0 = 0; k0 < K; k0 += 64) {
        uint4 vah[4], val[4], vwh[4], vwl[4];
        get64(vah, pAh + k0);
        get64(val, pAl + k0);
        get64(vwh, pWh + k0);
        get64(vwl, pWl + k0);
        __syncthreads();
        put64(&AhL[sr][sh], vah);
        put64(&AlL[sr][sh], val);
        put64(&WhL[sr][sh], vwh);
        put64(&WlL[sr][sh], vwl);
        __syncthreads();

        #pragma unroll
        for (int kk = 0; kk < 4; ++kk) {
            const int col = kk * 16 + g2 * 4;
            const s8v bh0 = ldfrag(&AhL[wm * 64 + l5][col]);
            const s8v bl0 = ldfrag(&AlL[wm * 64 + l5][col]);
            const s8v bh1 = ldfrag(&AhL[wm * 64 + 32 + l5][col]);
            const s8v bl1 = ldfrag(&AlL[wm * 64 + 32 + l5][col]);
            const s8v ah0 = ldfrag(&WhL[wn * 64 + l5][col]);
            const s8v al0 = ldfrag(&WlL[wn * 64 + l5][col]);
            const s8v ah1 = ldfrag(&WhL[wn * 64 + 32 + l5][col]);
            const s8v al1 = ldfrag(&WlL[wn * 64 + 32 + l5][col]);
            acc[0][0] = MFMA32(ah0, bh0, acc[0][0]);
            acc[0][0] = MFMA32(ah0, bl0, acc[0][0]);
            acc[0][0] = MFMA32(al0, bh0, acc[0][0]);
            acc[0][1] = MFMA32(ah1, bh0, acc[0][1]);
            acc[0][1] = MFMA32(ah1, bl0, acc[0][1]);
            acc[0][1] = MFMA32(al1, bh0, acc[0][1]);
            acc[1][0] = MFMA32(ah0, bh1, acc[1][0]);
            acc[1][0] = MFMA32(ah0, bl1, acc[1][0]);
            acc[1][0] = MFMA32(al0, bh1, acc[1][0]);
            acc[1][1] = MFMA32(ah1, bh1, acc[1][1]);
            acc[1][1] = MFMA32(ah1, bl1, acc[1][1]);
            acc[1][1] = MFMA32(al1, bh1, acc[1][1]);
        }
    }

    // epilogue: lane holds C[m][n] for m = m0+wm*64+mt*32+l5,
    // n = n0+wn*64+nt*32 + r4*8 + g2*4 + e
    #pragma unroll
    for (int mt = 0; mt < 2; ++mt) {
        const int m = m0 + wm * 64 + mt * 32 + l5;
        #pragma unroll
        for (int nt = 0; nt < 2; ++nt) {
            const int nb = n0 + wn * 64 + nt * 32;
            #pragma unroll
            for (int r4 = 0; r4 < 4; ++r4) {
                const int n = nb + r4 * 8 + g2 * 4;
                const float4 bv = *(const float4*)(bias + n);
                float o[4];
                o[0] = acc[mt][nt][r4 * 4 + 0] + bv.x;
                o[1] = acc[mt][nt][r4 * 4 + 1] + bv.y;
                o[2] = acc[mt][nt][r4 * 4 + 2] + bv.z;
                o[3] = acc[mt][nt][r4 * 4 + 3] + bv.w;
                if (EPI == 0) {
                    *(float4*)(Cout + (size_t)m * N + n) =
                        make_float4(o[0], o[1], o[2], o[3]);
                } else {
                    const u16x4 ah = *(const u16x4*)(cat_hi + (size_t)m * 1536 + n);
                    const u16x4 al = *(const u16x4*)(cat_lo + (size_t)m * 1536 + n);
                    const u16x4 bh = *(const u16x4*)(cat_hi + (size_t)m * 1536 + 768 + n);
                    const u16x4 bl = *(const u16x4*)(cat_lo + (size_t)m * 1536 + 768 + n);
                    u16x4 fh, fl;
                    #pragma unroll
                    for (int e = 0; e < 4; ++e) {
                        const float av  = bf2f(ah[e]) + bf2f(al[e]);
                        const float a1v = bf2f(bh[e]) + bf2f(bl[e]);
                        const float s = sigmoidf_(o[e]);
                        const float f = s * av + (1.f - s) * a1v;
                        const ushortT hi = f2bf(f);
                        fh[e] = hi;
                        fl[e] = f2bf(f - bf2f(hi));
                    }
                    *(u16x4*)(Fhi + (size_t)m * 768 + n) = fh;
                    *(u16x4*)(Flo + (size_t)m * 768 + n) = fl;
                }
            }
        }
    }
}

// ---------------------------------------------------------------------------
// Prep: qkv fp32 [4096][2304] -> per-(b,h) hi/lo bf16 Q,K + transposed V.
// ---------------------------------------------------------------------------
__global__ __launch_bounds__(256)
void prep_qkv(const float* __restrict__ qkv,
              ushortT* __restrict__ Qh, ushortT* __restrict__ Ql,
              ushortT* __restrict__ Kh, ushortT* __restrict__ Kl,
              ushortT* __restrict__ Vth, ushortT* __restrict__ Vtl)
{
    __shared__ float Vs[64][68];
    const int tid = threadIdx.x;
    const int s0 = blockIdx.x * 64;
    const int bh = blockIdx.y;
    const int b = bh / H_, h = bh % H_;

    #pragma unroll
    for (int j = 0; j < 4; ++j) {
        const int fid = j * 256 + tid;
        const int r = fid >> 4, c4 = (fid & 15) << 2;
        const int grow = b * S_ + s0 + r;
        const float4 q4 = *(const float4*)(qkv + (size_t)grow * 2304 + h * 64 + c4);
        const float4 k4 = *(const float4*)(qkv + (size_t)grow * 2304 + 768 + h * 64 + c4);
        const float4 v4 = *(const float4*)(qkv + (size_t)grow * 2304 + 1536 + h * 64 + c4);

        const size_t o = ((size_t)bh * S_ + s0 + r) * 64 + c4;
        u16x4 qh, ql, kh, kl;
        const float qa[4] = {q4.x, q4.y, q4.z, q4.w};
        const float ka[4] = {k4.x, k4.y, k4.z, k4.w};
        #pragma unroll
        for (int i = 0; i < 4; ++i) {
            ushortT hq = f2bf(qa[i]); qh[i] = hq; ql[i] = f2bf(qa[i] - bf2f(hq));
            ushortT hk = f2bf(ka[i]); kh[i] = hk; kl[i] = f2bf(ka[i] - bf2f(hk));
        }
        *(u16x4*)(Qh + o) = qh;
        *(u16x4*)(Ql + o) = ql;
        *(u16x4*)(Kh + o) = kh;
        *(u16x4*)(Kl + o) = kl;
        *(float4*)&Vs[r][c4] = v4;
    }
    __syncthreads();

    const int d = tid >> 2;
    const int sseg = (tid & 3) << 4;
    ushortT hh[16], ll[16];
    #pragma unroll
    for (int t = 0; t < 16; ++t) {
        const float f = Vs[sseg + t][d];
        const ushortT hi = f2bf(f);
        hh[t] = hi;
        ll[t] = f2bf(f - bf2f(hi));
    }
    const size_t vo = ((size_t)bh * 64 + d) * S_ + s0 + sseg;
    *(uint4*)(Vth + vo)     = ((const uint4*)hh)[0];
    *(uint4*)(Vth + vo + 8) = ((const uint4*)hh)[1];
    *(uint4*)(Vtl + vo)     = ((const uint4*)ll)[0];
    *(uint4*)(Vtl + vo + 8) = ((const uint4*)ll)[1];
}

// copy one 64x64 bf16 tile (row stride rs) into LDS [64][68]
__device__ __forceinline__ void stage64(ushortT* __restrict__ dst,
                                        const ushortT* __restrict__ src,
                                        int rs, int tid) {
    const int r = tid >> 1;
    const int half = (tid & 1) << 5;
    uint4 w[4];
    get64(w, src + (size_t)r * rs + half);
    put64(dst + r * 68 + half, w);
}

// ---------------------------------------------------------------------------
// MFMA flash self-attention (split-bf16, 3-term). 128 thr = 2 waves.
// Epilogue writes hi/lo bf16 into cat [BS][1536] cols h*64.. (a branch).
// ---------------------------------------------------------------------------
__global__ __launch_bounds__(128)
void attn_self_mfma(const ushortT* __restrict__ Qh, const ushortT* __restrict__ Ql,
                    const ushortT* __restrict__ Kh, const ushortT* __restrict__ Kl,
                    const ushortT* __restrict__ Vth, const ushortT* __restrict__ Vtl,
                    ushortT* __restrict__ cat_hi, ushortT* __restrict__ cat_lo)
{
    __shared__ ushortT KhL[64][68];
    __shared__ ushortT KlL[64][68];
    __shared__ ushortT VhL[64][68];
    __shared__ ushortT VlL[64][68];

    const int tid = threadIdx.x;
    const int lane = tid & 63;
    const int wv = tid >> 6;
    const int l5 = lane & 31;
    const int g2 = lane >> 5;
    const int q0 = blockIdx.x * 64;
    const int bh = blockIdx.y;
    const int b = bh / H_, h = bh % H_;

    const ushortT* QhB = Qh + ((size_t)bh * S_) * 64;
    const ushortT* QlB = Ql + ((size_t)bh * S_) * 64;
    const ushortT* KhB = Kh + ((size_t)bh * S_) * 64;
    const ushortT* KlB = Kl + ((size_t)bh * S_) * 64;
    const ushortT* VhB = Vth + ((size_t)bh * 64) * S_;
    const ushortT* VlB = Vtl + ((size_t)bh * 64) * S_;

    stage64(&KhL[0][0], QhB + (size_t)q0 * 64, 64, tid);
    stage64(&KlL[0][0], QlB + (size_t)q0 * 64, 64, tid);
    __syncthreads();
    s8v qh[4], ql[4];
    const int qrowL = wv * 32 + l5;
    #pragma unroll
    for (int t = 0; t < 4; ++t) {
        qh[t] = ldfrag(&KhL[qrowL][t * 16 + g2 * 4]);
        ql[t] = ldfrag(&KlL[qrowL][t * 16 + g2 * 4]);
    }
    __syncthreads();

    f32x16 O0, O1;
    #pragma unroll
    for (int i = 0; i < 16; ++i) { O0[i] = 0.f; O1[i] = 0.f; }
    float m = -3.0e38f, lsum = 0.f;

    for (int kt = 0; kt < S_ / 64; ++kt) {
        const int k0 = kt * 64;
        stage64(&KhL[0][0], KhB + (size_t)k0 * 64, 64, tid);
        stage64(&KlL[0][0], KlB + (size_t)k0 * 64, 64, tid);
        stage64(&VhL[0][0], VhB + k0, S_, tid);
        stage64(&VlL[0][0], VlB + k0, S_, tid);
        __syncthreads();

        f32x16 s0v, s1v;
        #pragma unroll
        for (int i = 0; i < 16; ++i) { s0v[i] = 0.f; s1v[i] = 0.f; }
        #pragma unroll
        for (int t = 0; t < 4; ++t) {
            const int col = t * 16 + g2 * 4;
            const s8v kh0 = ldfrag(&KhL[l5][col]);
            const s8v kl0 = ldfrag(&KlL[l5][col]);
            s0v = MFMA32(kh0, qh[t], s0v);
            s0v = MFMA32(kh0, ql[t], s0v);
            s0v = MFMA32(kl0, qh[t], s0v);
            const s8v kh1 = ldfrag(&KhL[32 + l5][col]);
            const s8v kl1 = ldfrag(&KlL[32 + l5][col]);
            s1v = MFMA32(kh1, qh[t], s1v);
            s1v = MFMA32(kh1, ql[t], s1v);
            s1v = MFMA32(kl1, qh[t], s1v);
        }

        float tmax = s0v[0];
        #pragma unroll
        for (int i = 1; i < 16; ++i) tmax = fmaxf(tmax, s0v[i]);
        #pragma unroll
        for (int i = 0; i < 16; ++i) tmax = fmaxf(tmax, s1v[i]);
        tmax = fmaxf(tmax, __shfl_xor(tmax, 32, 64));
        const float mn = fmaxf(m, tmax);
        const float sc = __expf(m - mn);
        m = mn;
        float rs = 0.f;
        #pragma unroll
        for (int i = 0; i < 16; ++i) { s0v[i] = __expf(s0v[i] - mn); rs += s0v[i]; }
        #pragma unroll
        for (int i = 0; i < 16; ++i) { s1v[i] = __expf(s1v[i] - mn); rs += s1v[i]; }
        rs += __shfl_xor(rs, 32, 64);
        lsum = lsum * sc + rs;
        #pragma unroll
        for (int i = 0; i < 16; ++i) { O0[i] *= sc; O1[i] *= sc; }

        s8v ph[4], pl[4];
        #pragma unroll
        for (int ks = 0; ks < 4; ++ks) {
            const int off = (ks & 1) * 8;
            #pragma unroll
            for (int j = 0; j < 8; ++j) {
                const float f = (ks < 2) ? s0v[off + j] : s1v[off + j];
                const ushortT hi = f2bf(f);
                ph[ks][j] = (short)hi;
                pl[ks][j] = (short)f2bf(f - bf2f(hi));
            }
        }

        #pragma unroll
        for (int ks = 0; ks < 4; ++ks) {
            const int col = ks * 16 + g2 * 4;
            const s8v vh0 = ldfrag(&VhL[l5][col]);
            const s8v vl0 = ldfrag(&VlL[l5][col]);
            O0 = MFMA32(vh0, ph[ks], O0);
            O0 = MFMA32(vh0, pl[ks], O0);
            O0 = MFMA32(vl0, ph[ks], O0);
            const s8v vh1 = ldfrag(&VhL[32 + l5][col]);
            const s8v vl1 = ldfrag(&VlL[32 + l5][col]);
            O1 = MFMA32(vh1, ph[ks], O1);
            O1 = MFMA32(vh1, pl[ks], O1);
            O1 = MFMA32(vl1, ph[ks], O1);
        }
        __syncthreads();
    }

    const float inv = 1.0f / lsum;
    const int grow = b * S_ + q0 + wv * 32 + l5;
    ushortT* hp = cat_hi + (size_t)grow * 1536 + h * 64;
    ushortT* lp = cat_lo + (size_t)grow * 1536 + h * 64;
    #pragma unroll
    for (int rb = 0; rb < 4; ++rb) {
        u16x4 h0, l0, h1, l1;
        #pragma unroll
        for (int e = 0; e < 4; ++e) {
            const float f0 = O0[rb * 4 + e] * inv;
            const float f1 = O1[rb * 4 + e] * inv;
            const ushortT i0 = f2bf(f0);
            const ushortT i1 = f2bf(f1);
            h0[e] = i0; l0[e] = f2bf(f0 - bf2f(i0));
            h1[e] = i1; l1[e] = f2bf(f1 - bf2f(i1));
        }
        *(u16x4*)(hp + rb * 8 + g2 * 4)      = h0;
        *(u16x4*)(lp + rb * 8 + g2 * 4)      = l0;
        *(u16x4*)(hp + 32 + rb * 8 + g2 * 4) = h1;
        *(u16x4*)(lp + 32 + rb * 8 + g2 * 4) = l1;
    }
}

// ---------------------------------------------------------------------------
// Memory attention (fp32 compute); q reconstructed from Qh+Ql (qkv fp32 is
// dead by now — its memory is reused for cat). Epilogue writes hi/lo bf16
// into cat cols 768 + h*64.. (a1 branch).
// ---------------------------------------------------------------------------
__global__ __launch_bounds__(256)
void attn_mem(const ushortT* __restrict__ Qh, const ushortT* __restrict__ Ql,
              const float* __restrict__ mkv,
              ushortT* __restrict__ cat_hi, ushortT* __restrict__ cat_lo)
{
    __shared__ float Qt[64][68];
    __shared__ float Kmt[64][112];
    __shared__ float Vm[100][68];
    __shared__ float Psm[64][104];

    const int tid = threadIdx.x;
    const int tx = tid & 15, ty = tid >> 4;
    const int q0 = blockIdx.x * 64;
    const int b = blockIdx.y / H_;
    const int h = blockIdx.y % H_;
    const int bh = blockIdx.y;

    #pragma unroll
    for (int j = 0; j < 4; ++j) {
        const int fid = j * 256 + tid;
        const int r = fid >> 4, c4 = (fid & 15) << 2;
        const size_t o = ((size_t)bh * S_ + q0 + r) * 64 + c4;
        const u16x4 qh = *(const u16x4*)(Qh + o);
        const u16x4 ql = *(const u16x4*)(Ql + o);
        #pragma unroll
        for (int e = 0; e < 4; ++e)
            Qt[c4 + e][r] = bf2f(qh[e]) + bf2f(ql[e]);
    }
    #pragma unroll
    for (int j = 0; j < 7; ++j) {
        const int fid = j * 256 + tid;
        if (fid < 1600) {
            const int r = fid >> 4, c4 = (fid & 15) << 2;
            const float4 k4 = *(const float4*)(mkv + (size_t)r * 1536 + h * 64 + c4);
            const float4 v4 = *(const float4*)(mkv + (size_t)r * 1536 + 768 + h * 64 + c4);
            Kmt[c4 + 0][r] = k4.x; Kmt[c4 + 1][r] = k4.y;
            Kmt[c4 + 2][r] = k4.z; Kmt[c4 + 3][r] = k4.w;
            *(float4*)&Vm[r][c4] = v4;
        }
    }
    for (int idx = tid; idx < 64 * 12; idx += 256) {
        Kmt[idx / 12][100 + idx % 12] = 0.f;
    }
    __syncthreads();

    float Sm[4][7] = {};
    #pragma unroll
    for (int d = 0; d < 64; ++d) {
        const float4 qa = *(const float4*)&Qt[d][ty << 2];
        const float qr[4] = {qa.x, qa.y, qa.z, qa.w};
        #pragma unroll
        for (int c = 0; c < 7; ++c) {
            const float kv = Kmt[d][tx + 16 * c];
            #pragma unroll
            for (int r = 0; r < 4; ++r)
                Sm[r][c] = fmaf(qr[r], kv, Sm[r][c]);
        }
    }

    float l[4];
    #pragma unroll
    for (int r = 0; r < 4; ++r) {
        float rm = -3.0e38f;
        #pragma unroll
        for (int c = 0; c < 7; ++c)
            if (tx + 16 * c < 100) rm = fmaxf(rm, Sm[r][c]);
        rm = fmaxf(rm, __shfl_xor(rm, 1, 64));
        rm = fmaxf(rm, __shfl_xor(rm, 2, 64));
        rm = fmaxf(rm, __shfl_xor(rm, 4, 64));
        rm = fmaxf(rm, __shfl_xor(rm, 8, 64));
        float s = 0.f;
        #pragma unroll
        for (int c = 0; c < 7; ++c) {
            const int jcol = tx + 16 * c;
            if (jcol < 100) {
                const float p = __expf(Sm[r][c] - rm);
                Psm[(ty << 2) + r][jcol] = p;
                s += p;
            }
        }
        s += __shfl_xor(s, 1, 64);
        s += __shfl_xor(s, 2, 64);
        s += __shfl_xor(s, 4, 64);
        s += __shfl_xor(s, 8, 64);
        l[r] = s;
    }
    __syncthreads();

    float acc[4][4] = {};
    for (int k = 0; k < 100; ++k) {
        const float4 va = *(const float4*)&Vm[k][tx << 2];
        const float vr[4] = {va.x, va.y, va.z, va.w};
        float pa[4];
        #pragma unroll
        for (int r = 0; r < 4; ++r) pa[r] = Psm[(ty << 2) + r][k];
        #pragma unroll
        for (int r = 0; r < 4; ++r)
            #pragma unroll
            for (int c = 0; c < 4; ++c)
                acc[r][c] = fmaf(pa[r], vr[c], acc[r][c]);
    }

    #pragma unroll
    for (int r = 0; r < 4; ++r) {
        const float inv = 1.0f / l[r];
        const int row = q0 + (ty << 2) + r;
        u16x4 hv, lv;
        #pragma unroll
        for (int e = 0; e < 4; ++e) {
            const float f = acc[r][e] * inv;
            const ushortT hi = f2bf(f);
            hv[e] = hi;
            lv[e] = f2bf(f - bf2f(hi));
        }
        const size_t o = (size_t)(b * S_ + row) * 1536 + 768 + h * 64 + (tx << 2);
        *(u16x4*)(cat_hi + o) = hv;
        *(u16x4*)(cat_lo + o) = lv;
    }
}

// ---------------------------------------------------------------------------
extern "C" void kernel_launch(void* const* d_in, const int* in_sizes, int n_in,
                              void* d_out, int out_size, void* d_ws, size_t ws_size,
                              hipStream_t stream)
{
    const float* x       = (const float*)d_in[0];
    const float* w_attn  = (const float*)d_in[1];
    const float* b_attn  = (const float*)d_in[2];
    const float* w_proj  = (const float*)d_in[3];
    const float* b_proj  = (const float*)d_in[4];
    const float* w_mem   = (const float*)d_in[5];
    const float* b_mem   = (const float*)d_in[6];
    const float* w_alpha = (const float*)d_in[7];
    const float* b_alpha = (const float*)d_in[8];
    const float* memf    = (const float*)d_in[9];
    float* out = (float*)d_out;

    const int B = in_sizes[0] / (S_ * C_);   // 2
    const int BS = B * S_;                   // 4096

    // ---- workspace layout (~90 MB; alias lifetimes in comments) ----
    float* ws   = (float*)d_ws;
    float* qkv  = ws;                                 // [BS][2304] fp32; dies at prep_qkv; slab reused as cat
    float* mkvb = qkv + (size_t)BS * 2304;            // [100][1536] fp32
    ushortT* u  = (ushortT*)(mkvb + (size_t)M_ * 1536);

    const size_t XS   = (size_t)BS * C_;              // 3,145,728
    const size_t CATS = (size_t)BS * 2 * C_;          // 6,291,456
    const size_t SLAB = (size_t)B * H_ * S_ * 64;     // 3,145,728
    ushortT* x_hi   = u;            ushortT* x_lo   = x_hi + XS;  // x dies at qkv GEMM
    ushortT* wqT_hi = x_lo + XS;    ushortT* wqT_lo = wqT_hi + (size_t)2304 * 768;
    ushortT* waT_hi = wqT_lo + (size_t)2304 * 768;
    ushortT* waT_lo = waT_hi + (size_t)768 * 1536;
    ushortT* wpT_hi = waT_lo + (size_t)768 * 1536;
    ushortT* wpT_lo = wpT_hi + (size_t)768 * 768;
    ushortT* Qh  = wpT_lo + (size_t)768 * 768;
    ushortT* Ql  = Qh + SLAB;
    ushortT* Kh  = Ql + SLAB;
    ushortT* Kl  = Kh + SLAB;
    // aliases:
    //   Vth/Vtl -> dead x slab (written by prep_qkv, read by attn_self)
    //   f_hi/f_lo -> same slab again (written by alpha GEMM after attn_self)
    //   cat -> dead qkv fp32 slab (25.2 MB inside 37.7 MB)
    ushortT* Vth = x_hi;
    ushortT* Vtl = x_lo;
    ushortT* cat_hi = (ushortT*)qkv;
    ushortT* cat_lo = cat_hi + CATS;
    ushortT* f_hi   = x_hi;
    ushortT* f_lo   = x_lo;

    const dim3 blk(256);

    // weight transpose+split
    prep_wT<<<dim3(2304 / 64, 768 / 64), blk, 0, stream>>>(w_attn, wqT_hi, wqT_lo, 768, 2304);
    prep_wT<<<dim3(768 / 64, 1536 / 64), blk, 0, stream>>>(w_alpha, waT_hi, waT_lo, 1536, 768);
    prep_wT<<<dim3(768 / 64, 768 / 64), blk, 0, stream>>>(w_proj, wpT_hi, wpT_lo, 768, 768);

    // x -> hi/lo bf16
    prep_split<<<dim3((int)(XS / 4 / 256)), blk, 0, stream>>>(x, x_hi, x_lo, (int)(XS / 4));

    // qkv = x @ w_attn + b_attn   (split-bf16 MFMA); x dead after this
    gemm_mfma<0><<<dim3(2304 / 128, BS / 128), blk, 0, stream>>>(
        x_hi, x_lo, wqT_hi, wqT_lo, b_attn, qkv,
        nullptr, nullptr, nullptr, nullptr, BS, 2304, 768);

    // mkv = mem @ w_mem + b_mem   (tiny, fp32)
    gemm64<<<dim3(1536 / 64, 2), blk, 0, stream>>>(memf, w_mem, b_mem, mkvb, M_, 1536, 768);

    // split q/k/v -> hi/lo bf16 (V transposed into dead x slab); qkv fp32 dead after this
    prep_qkv<<<dim3(S_ / 64, B * H_), blk, 0, stream>>>(qkv, Qh, Ql, Kh, Kl, Vth, Vtl);

    // a -> cat[:, 0:768]  (split-bf16 MFMA flash attention; cat overwrites qkv slab)
    attn_self_mfma<<<dim3(S_ / 64, B * H_), dim3(128), 0, stream>>>(
        Qh, Ql, Kh, Kl, Vth, Vtl, cat_hi, cat_lo);

    // a1 -> cat[:, 768:1536]  (fp32 memory attention; q from Qh+Ql)
    attn_mem<<<dim3(S_ / 64, B * H_), blk, 0, stream>>>(Qh, Ql, mkvb, cat_hi, cat_lo);

    // fused = gate(cat @ w_alpha + b_alpha) -> hi/lo bf16 (into dead V/x slab)
    gemm_mfma<1><<<dim3(768 / 128, BS / 128), blk, 0, stream>>>(
        cat_hi, cat_lo, waT_hi, waT_lo, b_alpha, nullptr,
        cat_hi, cat_lo, f_hi, f_lo, BS, 768, 1536);

    // out = fused @ w_proj + b_proj  (fp32 out)
    gemm_mfma<0><<<dim3(768 / 128, BS / 128), blk, 0, stream>>>(
        f_hi, f_lo, wpT_hi, wpT_lo, b_proj, out,
        nullptr, nullptr, nullptr, nullptr, BS, 768, 768);
}

// Round 9
// 482.838 us; speedup vs baseline: 3.0437x; 1.5682x over previous
//
#include <hip/hip_runtime.h>
#include <math.h>

constexpr int C_ = 768;
constexpr int S_ = 2048;
constexpr int H_ = 12;
constexpr int M_ = 100;

typedef unsigned short ushortT;
typedef unsigned long long ull;
typedef short s8v __attribute__((ext_vector_type(8)));
typedef float f32x16 __attribute__((ext_vector_type(16)));
typedef unsigned short u16x4 __attribute__((ext_vector_type(4)));

__device__ __forceinline__ float sigmoidf_(float x) {
    return 1.0f / (1.0f + __expf(-x));
}
__device__ __forceinline__ ushortT f2bf(float f) {
    unsigned int u = __float_as_uint(f);
    u += 0x7FFFu + ((u >> 16) & 1u);
    return (ushortT)(u >> 16);
}
__device__ __forceinline__ float bf2f(ushortT h) {
    return __uint_as_float(((unsigned int)h) << 16);
}

// ---------------------------------------------------------------------------
// fp32 tiled GEMM — used only for the tiny mkv GEMM (100x1536, K=768).
// ---------------------------------------------------------------------------
__global__ __launch_bounds__(256)
void gemm64(const float* __restrict__ A, const float* __restrict__ W,
            const float* __restrict__ bias, float* __restrict__ Cout,
            int M, int N, int K)
{
    constexpr int BM = 64, BN = 64, BK = 16;
    __shared__ float As[BK][BM + 4];
    __shared__ float Ws[BK][BN];

    const int tid = threadIdx.x;
    const int tx = tid & 15, ty = tid >> 4;
    const int row0 = blockIdx.y * BM, col0 = blockIdx.x * BN;
    const int ar = tid >> 2, ac4 = (tid & 3) << 2;

    float acc[4][4] = {};

    for (int k0 = 0; k0 < K; k0 += BK) {
        float4 av = make_float4(0.f, 0.f, 0.f, 0.f);
        const int grow = row0 + ar;
        const int gk = k0 + ac4;
        if (grow < M) av = *(const float4*)(A + (size_t)grow * K + gk);
        const float4 wv = *(const float4*)(W + (size_t)(k0 + ty) * N + col0 + (tx << 2));

        __syncthreads();
        As[ac4 + 0][ar] = av.x;
        As[ac4 + 1][ar] = av.y;
        As[ac4 + 2][ar] = av.z;
        As[ac4 + 3][ar] = av.w;
        *(float4*)&Ws[ty][tx << 2] = wv;
        __syncthreads();

        #pragma unroll
        for (int kk = 0; kk < BK; ++kk) {
            const float4 a4 = *(const float4*)&As[kk][ty << 2];
            const float4 b4 = *(const float4*)&Ws[kk][tx << 2];
            const float arr[4] = {a4.x, a4.y, a4.z, a4.w};
            const float brr[4] = {b4.x, b4.y, b4.z, b4.w};
            #pragma unroll
            for (int i = 0; i < 4; ++i)
                #pragma unroll
                for (int j = 0; j < 4; ++j)
                    acc[i][j] = fmaf(arr[i], brr[j], acc[i][j]);
        }
    }

    const int crow0 = row0 + (ty << 2);
    const int ccol = col0 + (tx << 2);
    const float4 bv = *(const float4*)(bias + ccol);
    #pragma unroll
    for (int r = 0; r < 4; ++r) {
        const int crow = crow0 + r;
        if (crow >= M) continue;
        float4 o;
        o.x = acc[r][0] + bv.x;
        o.y = acc[r][1] + bv.y;
        o.z = acc[r][2] + bv.z;
        o.w = acc[r][3] + bv.w;
        *(float4*)(Cout + (size_t)crow * N + ccol) = o;
    }
}

// ---------------------------------------------------------------------------
// Weight prep: W [K][N] fp32 -> WT hi/lo bf16 [N][K] (transpose + split).
// ---------------------------------------------------------------------------
__global__ __launch_bounds__(256)
void prep_wT(const float* __restrict__ W, ushortT* __restrict__ Thi,
             ushortT* __restrict__ Tlo, int K, int N)
{
    __shared__ float Ts[64][65];
    const int tid = threadIdx.x;
    const int n0 = blockIdx.x * 64, k0 = blockIdx.y * 64;
    #pragma unroll
    for (int j = 0; j < 4; ++j) {
        const int row = (tid >> 4) + j * 16;
        const int c4 = (tid & 15) << 2;
        *(float4*)&Ts[row][c4] = *(const float4*)(W + (size_t)(k0 + row) * N + n0 + c4);
    }
    __syncthreads();
    const int nr = tid >> 2, ks = (tid & 3) << 4;
    u16x4 hv[4], lv[4];
    #pragma unroll
    for (int t = 0; t < 16; ++t) {
        const float f = Ts[ks + t][nr];
        const ushortT hi = f2bf(f);
        hv[t >> 2][t & 3] = hi;
        lv[t >> 2][t & 3] = f2bf(f - bf2f(hi));
    }
    ushortT* ph = Thi + (size_t)(n0 + nr) * K + k0 + ks;
    ushortT* pl = Tlo + (size_t)(n0 + nr) * K + k0 + ks;
    #pragma unroll
    for (int q = 0; q < 4; ++q) {
        *(u16x4*)(ph + q * 4) = hv[q];
        *(u16x4*)(pl + q * 4) = lv[q];
    }
}

// ---------------------------------------------------------------------------
// Elementwise split: X fp32 -> hi/lo bf16 (same layout).
// ---------------------------------------------------------------------------
__global__ __launch_bounds__(256)
void prep_split(const float* __restrict__ X, ushortT* __restrict__ Xhi,
                ushortT* __restrict__ Xlo, int n4)
{
    const int i = blockIdx.x * 256 + threadIdx.x;
    if (i >= n4) return;
    const float4 v = ((const float4*)X)[i];
    const float a[4] = {v.x, v.y, v.z, v.w};
    u16x4 h, l;
    #pragma unroll
    for (int e = 0; e < 4; ++e) {
        const ushortT hi = f2bf(a[e]);
        h[e] = hi;
        l[e] = f2bf(a[e] - bf2f(hi));
    }
    ((u16x4*)Xhi)[i] = h;
    ((u16x4*)Xlo)[i] = l;
}

// ---------------------------------------------------------------------------
// Memory-KV prep: mkv fp32 [100][1536] -> per-head padded hi/lo bf16:
//   Kmh/Kml [12][128][64] (slots 100..127 zero), Vmth/Vmtl [12][64][128]
//   (transposed, slots 100..127 zero). Tiny (~0.8 MB), 12 blocks.
// ---------------------------------------------------------------------------
__global__ __launch_bounds__(256)
void prep_mkv(const float* __restrict__ mkv,
              ushortT* __restrict__ Kmh, ushortT* __restrict__ Kml,
              ushortT* __restrict__ Vmth, ushortT* __restrict__ Vmtl)
{
    const int h = blockIdx.x;
    const int tid = threadIdx.x;
    // K: [slot][d] layout, zero-padded slots
    for (int idx = tid; idx < 128 * 64; idx += 256) {
        const int slot = idx >> 6, d = idx & 63;
        float f = 0.f;
        if (slot < M_) f = mkv[(size_t)slot * 1536 + h * 64 + d];
        const ushortT hi = f2bf(f);
        Kmh[(size_t)h * 8192 + idx] = hi;
        Kml[(size_t)h * 8192 + idx] = f2bf(f - bf2f(hi));
    }
    // V^T: [d][slot] layout, zero-padded slots
    for (int idx = tid; idx < 64 * 128; idx += 256) {
        const int d = idx >> 7, slot = idx & 127;
        float f = 0.f;
        if (slot < M_) f = mkv[(size_t)slot * 1536 + 768 + h * 64 + d];
        const ushortT hi = f2bf(f);
        Vmth[(size_t)h * 8192 + idx] = hi;
        Vmtl[(size_t)h * 8192 + idx] = f2bf(f - bf2f(hi));
    }
}

// ---------------------------------------------------------------------------
// MFMA helpers (32x32x16 bf16). Fragment reads from [.][68]-padded LDS rows.
// ---------------------------------------------------------------------------
__device__ __forceinline__ s8v ldfrag(const ushortT* p) {
    union { s8v v; ull q[2]; } u;
    u.q[0] = *(const ull*)(p);
    u.q[1] = *(const ull*)(p + 8);
    return u.v;
}
__device__ __forceinline__ void get64(uint4* v, const ushortT* s) {
    v[0] = *(const uint4*)(s);
    v[1] = *(const uint4*)(s + 8);
    v[2] = *(const uint4*)(s + 16);
    v[3] = *(const uint4*)(s + 24);
}
__device__ __forceinline__ void put64(ushortT* dst, const uint4* v) {
    uint2* d = (uint2*)dst;
    d[0] = make_uint2(v[0].x, v[0].y); d[1] = make_uint2(v[0].z, v[0].w);
    d[2] = make_uint2(v[1].x, v[1].y); d[3] = make_uint2(v[1].z, v[1].w);
    d[4] = make_uint2(v[2].x, v[2].y); d[5] = make_uint2(v[2].z, v[2].w);
    d[6] = make_uint2(v[3].x, v[3].y); d[7] = make_uint2(v[3].z, v[3].w);
}
#define MFMA32(a, b, c) __builtin_amdgcn_mfma_f32_32x32x16_bf16(a, b, c, 0, 0, 0)

// ---------------------------------------------------------------------------
// Split-bf16 MFMA GEMM: C[M,N] = (Ahi+Alo)[M,K] @ (WThi+WTlo)^T + bias.
// 3-term (drops lo*lo). BM=BN=128, BK=64, 256 thr = 4 waves, each 64x64
// (four 32x32 acc tiles). EPI 0: Cout fp32. EPI 1: sigmoid-gate epilogue.
// ---------------------------------------------------------------------------
template<int EPI>
__global__ __launch_bounds__(256)
void gemm_mfma(const ushortT* __restrict__ Ahi, const ushortT* __restrict__ Alo,
               const ushortT* __restrict__ WThi, const ushortT* __restrict__ WTlo,
               const float* __restrict__ bias, float* __restrict__ Cout,
               const ushortT* __restrict__ cat_hi, const ushortT* __restrict__ cat_lo,
               ushortT* __restrict__ Fhi, ushortT* __restrict__ Flo,
               int M, int N, int K)
{
    __shared__ ushortT AhL[128][68];
    __shared__ ushortT AlL[128][68];
    __shared__ ushortT WhL[128][68];
    __shared__ ushortT WlL[128][68];

    const int tid = threadIdx.x, lane = tid & 63, wv = tid >> 6;
    const int l5 = lane & 31, g2 = lane >> 5;
    const int wm = wv & 1, wn = wv >> 1;
    const int m0 = blockIdx.y * 128, n0 = blockIdx.x * 128;
    const int sr = tid >> 1, sh = (tid & 1) << 5;

    f32x16 acc[2][2];
    #pragma unroll
    for (int i = 0; i < 16; ++i) {
        acc[0][0][i] = 0.f; acc[0][1][i] = 0.f;
        acc[1][0][i] = 0.f; acc[1][1][i] = 0.f;
    }

    const ushortT* pAh = Ahi + (size_t)(m0 + sr) * K + sh;
    const ushortT* pAl = Alo + (size_t)(m0 + sr) * K + sh;
    const ushortT* pWh = WThi + (size_t)(n0 + sr) * K + sh;
    const ushortT* pWl = WTlo + (size_t)(n0 + sr) * K + sh;

    for (int k0 = 0; k0 < K; k0 += 64) {
        uint4 vah[4], val[4], vwh[4], vwl[4];
        get64(vah, pAh + k0);
        get64(val, pAl + k0);
        get64(vwh, pWh + k0);
        get64(vwl, pWl + k0);
        __syncthreads();
        put64(&AhL[sr][sh], vah);
        put64(&AlL[sr][sh], val);
        put64(&WhL[sr][sh], vwh);
        put64(&WlL[sr][sh], vwl);
        __syncthreads();

        #pragma unroll
        for (int kk = 0; kk < 4; ++kk) {
            const int col = kk * 16 + g2 * 4;
            const s8v bh0 = ldfrag(&AhL[wm * 64 + l5][col]);
            const s8v bl0 = ldfrag(&AlL[wm * 64 + l5][col]);
            const s8v bh1 = ldfrag(&AhL[wm * 64 + 32 + l5][col]);
            const s8v bl1 = ldfrag(&AlL[wm * 64 + 32 + l5][col]);
            const s8v ah0 = ldfrag(&WhL[wn * 64 + l5][col]);
            const s8v al0 = ldfrag(&WlL[wn * 64 + l5][col]);
            const s8v ah1 = ldfrag(&WhL[wn * 64 + 32 + l5][col]);
            const s8v al1 = ldfrag(&WlL[wn * 64 + 32 + l5][col]);
            acc[0][0] = MFMA32(ah0, bh0, acc[0][0]);
            acc[0][0] = MFMA32(ah0, bl0, acc[0][0]);
            acc[0][0] = MFMA32(al0, bh0, acc[0][0]);
            acc[0][1] = MFMA32(ah1, bh0, acc[0][1]);
            acc[0][1] = MFMA32(ah1, bl0, acc[0][1]);
            acc[0][1] = MFMA32(al1, bh0, acc[0][1]);
            acc[1][0] = MFMA32(ah0, bh1, acc[1][0]);
            acc[1][0] = MFMA32(ah0, bl1, acc[1][0]);
            acc[1][0] = MFMA32(al0, bh1, acc[1][0]);
            acc[1][1] = MFMA32(ah1, bh1, acc[1][1]);
            acc[1][1] = MFMA32(ah1, bl1, acc[1][1]);
            acc[1][1] = MFMA32(al1, bh1, acc[1][1]);
        }
    }

    // epilogue: lane holds C[m][n] for m = m0+wm*64+mt*32+l5,
    // n = n0+wn*64+nt*32 + r4*8 + g2*4 + e
    #pragma unroll
    for (int mt = 0; mt < 2; ++mt) {
        const int m = m0 + wm * 64 + mt * 32 + l5;
        #pragma unroll
        for (int nt = 0; nt < 2; ++nt) {
            const int nb = n0 + wn * 64 + nt * 32;
            #pragma unroll
            for (int r4 = 0; r4 < 4; ++r4) {
                const int n = nb + r4 * 8 + g2 * 4;
                const float4 bv = *(const float4*)(bias + n);
                float o[4];
                o[0] = acc[mt][nt][r4 * 4 + 0] + bv.x;
                o[1] = acc[mt][nt][r4 * 4 + 1] + bv.y;
                o[2] = acc[mt][nt][r4 * 4 + 2] + bv.z;
                o[3] = acc[mt][nt][r4 * 4 + 3] + bv.w;
                if (EPI == 0) {
                    *(float4*)(Cout + (size_t)m * N + n) =
                        make_float4(o[0], o[1], o[2], o[3]);
                } else {
                    const u16x4 ah = *(const u16x4*)(cat_hi + (size_t)m * 1536 + n);
                    const u16x4 al = *(const u16x4*)(cat_lo + (size_t)m * 1536 + n);
                    const u16x4 bh = *(const u16x4*)(cat_hi + (size_t)m * 1536 + 768 + n);
                    const u16x4 bl = *(const u16x4*)(cat_lo + (size_t)m * 1536 + 768 + n);
                    u16x4 fh, fl;
                    #pragma unroll
                    for (int e = 0; e < 4; ++e) {
                        const float av  = bf2f(ah[e]) + bf2f(al[e]);
                        const float a1v = bf2f(bh[e]) + bf2f(bl[e]);
                        const float s = sigmoidf_(o[e]);
                        const float f = s * av + (1.f - s) * a1v;
                        const ushortT hi = f2bf(f);
                        fh[e] = hi;
                        fl[e] = f2bf(f - bf2f(hi));
                    }
                    *(u16x4*)(Fhi + (size_t)m * 768 + n) = fh;
                    *(u16x4*)(Flo + (size_t)m * 768 + n) = fl;
                }
            }
        }
    }
}

// ---------------------------------------------------------------------------
// Prep: qkv fp32 [4096][2304] -> per-(b,h) hi/lo bf16 Q,K + transposed V.
// ---------------------------------------------------------------------------
__global__ __launch_bounds__(256)
void prep_qkv(const float* __restrict__ qkv,
              ushortT* __restrict__ Qh, ushortT* __restrict__ Ql,
              ushortT* __restrict__ Kh, ushortT* __restrict__ Kl,
              ushortT* __restrict__ Vth, ushortT* __restrict__ Vtl)
{
    __shared__ float Vs[64][68];
    const int tid = threadIdx.x;
    const int s0 = blockIdx.x * 64;
    const int bh = blockIdx.y;
    const int b = bh / H_, h = bh % H_;

    #pragma unroll
    for (int j = 0; j < 4; ++j) {
        const int fid = j * 256 + tid;
        const int r = fid >> 4, c4 = (fid & 15) << 2;
        const int grow = b * S_ + s0 + r;
        const float4 q4 = *(const float4*)(qkv + (size_t)grow * 2304 + h * 64 + c4);
        const float4 k4 = *(const float4*)(qkv + (size_t)grow * 2304 + 768 + h * 64 + c4);
        const float4 v4 = *(const float4*)(qkv + (size_t)grow * 2304 + 1536 + h * 64 + c4);

        const size_t o = ((size_t)bh * S_ + s0 + r) * 64 + c4;
        u16x4 qh, ql, kh, kl;
        const float qa[4] = {q4.x, q4.y, q4.z, q4.w};
        const float ka[4] = {k4.x, k4.y, k4.z, k4.w};
        #pragma unroll
        for (int i = 0; i < 4; ++i) {
            ushortT hq = f2bf(qa[i]); qh[i] = hq; ql[i] = f2bf(qa[i] - bf2f(hq));
            ushortT hk = f2bf(ka[i]); kh[i] = hk; kl[i] = f2bf(ka[i] - bf2f(hk));
        }
        *(u16x4*)(Qh + o) = qh;
        *(u16x4*)(Ql + o) = ql;
        *(u16x4*)(Kh + o) = kh;
        *(u16x4*)(Kl + o) = kl;
        *(float4*)&Vs[r][c4] = v4;
    }
    __syncthreads();

    const int d = tid >> 2;
    const int sseg = (tid & 3) << 4;
    ushortT hh[16], ll[16];
    #pragma unroll
    for (int t = 0; t < 16; ++t) {
        const float f = Vs[sseg + t][d];
        const ushortT hi = f2bf(f);
        hh[t] = hi;
        ll[t] = f2bf(f - bf2f(hi));
    }
    const size_t vo = ((size_t)bh * 64 + d) * S_ + s0 + sseg;
    *(uint4*)(Vth + vo)     = ((const uint4*)hh)[0];
    *(uint4*)(Vth + vo + 8) = ((const uint4*)hh)[1];
    *(uint4*)(Vtl + vo)     = ((const uint4*)ll)[0];
    *(uint4*)(Vtl + vo + 8) = ((const uint4*)ll)[1];
}

// copy one 64x64 bf16 tile (row stride rs) into LDS [64][68]
__device__ __forceinline__ void stage64(ushortT* __restrict__ dst,
                                        const ushortT* __restrict__ src,
                                        int rs, int tid) {
    const int r = tid >> 1;
    const int half = (tid & 1) << 5;
    uint4 w[4];
    get64(w, src + (size_t)r * rs + half);
    put64(dst + r * 68 + half, w);
}

// ---------------------------------------------------------------------------
// MFMA flash self-attention (split-bf16, 3-term). 128 thr = 2 waves.
// Epilogue writes hi/lo bf16 into cat [BS][1536] cols h*64.. (a branch).
// ---------------------------------------------------------------------------
__global__ __launch_bounds__(128)
void attn_self_mfma(const ushortT* __restrict__ Qh, const ushortT* __restrict__ Ql,
                    const ushortT* __restrict__ Kh, const ushortT* __restrict__ Kl,
                    const ushortT* __restrict__ Vth, const ushortT* __restrict__ Vtl,
                    ushortT* __restrict__ cat_hi, ushortT* __restrict__ cat_lo)
{
    __shared__ ushortT KhL[64][68];
    __shared__ ushortT KlL[64][68];
    __shared__ ushortT VhL[64][68];
    __shared__ ushortT VlL[64][68];

    const int tid = threadIdx.x;
    const int lane = tid & 63;
    const int wv = tid >> 6;
    const int l5 = lane & 31;
    const int g2 = lane >> 5;
    const int q0 = blockIdx.x * 64;
    const int bh = blockIdx.y;
    const int b = bh / H_, h = bh % H_;

    const ushortT* QhB = Qh + ((size_t)bh * S_) * 64;
    const ushortT* QlB = Ql + ((size_t)bh * S_) * 64;
    const ushortT* KhB = Kh + ((size_t)bh * S_) * 64;
    const ushortT* KlB = Kl + ((size_t)bh * S_) * 64;
    const ushortT* VhB = Vth + ((size_t)bh * 64) * S_;
    const ushortT* VlB = Vtl + ((size_t)bh * 64) * S_;

    stage64(&KhL[0][0], QhB + (size_t)q0 * 64, 64, tid);
    stage64(&KlL[0][0], QlB + (size_t)q0 * 64, 64, tid);
    __syncthreads();
    s8v qh[4], ql[4];
    const int qrowL = wv * 32 + l5;
    #pragma unroll
    for (int t = 0; t < 4; ++t) {
        qh[t] = ldfrag(&KhL[qrowL][t * 16 + g2 * 4]);
        ql[t] = ldfrag(&KlL[qrowL][t * 16 + g2 * 4]);
    }
    __syncthreads();

    f32x16 O0, O1;
    #pragma unroll
    for (int i = 0; i < 16; ++i) { O0[i] = 0.f; O1[i] = 0.f; }
    float m = -3.0e38f, lsum = 0.f;

    for (int kt = 0; kt < S_ / 64; ++kt) {
        const int k0 = kt * 64;
        stage64(&KhL[0][0], KhB + (size_t)k0 * 64, 64, tid);
        stage64(&KlL[0][0], KlB + (size_t)k0 * 64, 64, tid);
        stage64(&VhL[0][0], VhB + k0, S_, tid);
        stage64(&VlL[0][0], VlB + k0, S_, tid);
        __syncthreads();

        f32x16 s0v, s1v;
        #pragma unroll
        for (int i = 0; i < 16; ++i) { s0v[i] = 0.f; s1v[i] = 0.f; }
        #pragma unroll
        for (int t = 0; t < 4; ++t) {
            const int col = t * 16 + g2 * 4;
            const s8v kh0 = ldfrag(&KhL[l5][col]);
            const s8v kl0 = ldfrag(&KlL[l5][col]);
            s0v = MFMA32(kh0, qh[t], s0v);
            s0v = MFMA32(kh0, ql[t], s0v);
            s0v = MFMA32(kl0, qh[t], s0v);
            const s8v kh1 = ldfrag(&KhL[32 + l5][col]);
            const s8v kl1 = ldfrag(&KlL[32 + l5][col]);
            s1v = MFMA32(kh1, qh[t], s1v);
            s1v = MFMA32(kh1, ql[t], s1v);
            s1v = MFMA32(kl1, qh[t], s1v);
        }

        float tmax = s0v[0];
        #pragma unroll
        for (int i = 1; i < 16; ++i) tmax = fmaxf(tmax, s0v[i]);
        #pragma unroll
        for (int i = 0; i < 16; ++i) tmax = fmaxf(tmax, s1v[i]);
        tmax = fmaxf(tmax, __shfl_xor(tmax, 32, 64));
        const float mn = fmaxf(m, tmax);
        const float sc = __expf(m - mn);
        m = mn;
        float rs = 0.f;
        #pragma unroll
        for (int i = 0; i < 16; ++i) { s0v[i] = __expf(s0v[i] - mn); rs += s0v[i]; }
        #pragma unroll
        for (int i = 0; i < 16; ++i) { s1v[i] = __expf(s1v[i] - mn); rs += s1v[i]; }
        rs += __shfl_xor(rs, 32, 64);
        lsum = lsum * sc + rs;
        #pragma unroll
        for (int i = 0; i < 16; ++i) { O0[i] *= sc; O1[i] *= sc; }

        s8v ph[4], pl[4];
        #pragma unroll
        for (int ks = 0; ks < 4; ++ks) {
            const int off = (ks & 1) * 8;
            #pragma unroll
            for (int j = 0; j < 8; ++j) {
                const float f = (ks < 2) ? s0v[off + j] : s1v[off + j];
                const ushortT hi = f2bf(f);
                ph[ks][j] = (short)hi;
                pl[ks][j] = (short)f2bf(f - bf2f(hi));
            }
        }

        #pragma unroll
        for (int ks = 0; ks < 4; ++ks) {
            const int col = ks * 16 + g2 * 4;
            const s8v vh0 = ldfrag(&VhL[l5][col]);
            const s8v vl0 = ldfrag(&VlL[l5][col]);
            O0 = MFMA32(vh0, ph[ks], O0);
            O0 = MFMA32(vh0, pl[ks], O0);
            O0 = MFMA32(vl0, ph[ks], O0);
            const s8v vh1 = ldfrag(&VhL[32 + l5][col]);
            const s8v vl1 = ldfrag(&VlL[32 + l5][col]);
            O1 = MFMA32(vh1, ph[ks], O1);
            O1 = MFMA32(vh1, pl[ks], O1);
            O1 = MFMA32(vl1, ph[ks], O1);
        }
        __syncthreads();
    }

    const float inv = 1.0f / lsum;
    const int grow = b * S_ + q0 + wv * 32 + l5;
    ushortT* hp = cat_hi + (size_t)grow * 1536 + h * 64;
    ushortT* lp = cat_lo + (size_t)grow * 1536 + h * 64;
    #pragma unroll
    for (int rb = 0; rb < 4; ++rb) {
        u16x4 h0, l0, h1, l1;
        #pragma unroll
        for (int e = 0; e < 4; ++e) {
            const float f0 = O0[rb * 4 + e] * inv;
            const float f1 = O1[rb * 4 + e] * inv;
            const ushortT i0 = f2bf(f0);
            const ushortT i1 = f2bf(f1);
            h0[e] = i0; l0[e] = f2bf(f0 - bf2f(i0));
            h1[e] = i1; l1[e] = f2bf(f1 - bf2f(i1));
        }
        *(u16x4*)(hp + rb * 8 + g2 * 4)      = h0;
        *(u16x4*)(lp + rb * 8 + g2 * 4)      = l0;
        *(u16x4*)(hp + 32 + rb * 8 + g2 * 4) = h1;
        *(u16x4*)(lp + 32 + rb * 8 + g2 * 4) = l1;
    }
}

// ---------------------------------------------------------------------------
// MFMA memory attention (split-bf16, 3-term). Same structure as attn_self
// but exactly 2 padded KV tiles (128 slots, 100 valid). Pad slots masked to
// -inf before softmax (kv = tile*64 + half*32 + (reg&3)+8(reg>>2)+4*g2).
// Writes hi/lo bf16 into cat cols 768 + h*64.. (a1 branch).
// ---------------------------------------------------------------------------
__global__ __launch_bounds__(128)
void attn_mem_mfma(const ushortT* __restrict__ Qh, const ushortT* __restrict__ Ql,
                   const ushortT* __restrict__ Kmh, const ushortT* __restrict__ Kml,
                   const ushortT* __restrict__ Vmth, const ushortT* __restrict__ Vmtl,
                   ushortT* __restrict__ cat_hi, ushortT* __restrict__ cat_lo)
{
    __shared__ ushortT KhL[64][68];
    __shared__ ushortT KlL[64][68];
    __shared__ ushortT VhL[64][68];
    __shared__ ushortT VlL[64][68];

    const int tid = threadIdx.x;
    const int lane = tid & 63;
    const int wv = tid >> 6;
    const int l5 = lane & 31;
    const int g2 = lane >> 5;
    const int q0 = blockIdx.x * 64;
    const int bh = blockIdx.y;
    const int b = bh / H_, h = bh % H_;

    const ushortT* QhB = Qh + ((size_t)bh * S_) * 64;
    const ushortT* QlB = Ql + ((size_t)bh * S_) * 64;
    const ushortT* KhB = Kmh + (size_t)h * 8192;    // [128][64]
    const ushortT* KlB = Kml + (size_t)h * 8192;
    const ushortT* VhB = Vmth + (size_t)h * 8192;   // [64][128]
    const ushortT* VlB = Vmtl + (size_t)h * 8192;

    stage64(&KhL[0][0], QhB + (size_t)q0 * 64, 64, tid);
    stage64(&KlL[0][0], QlB + (size_t)q0 * 64, 64, tid);
    __syncthreads();
    s8v qh[4], ql[4];
    const int qrowL = wv * 32 + l5;
    #pragma unroll
    for (int t = 0; t < 4; ++t) {
        qh[t] = ldfrag(&KhL[qrowL][t * 16 + g2 * 4]);
        ql[t] = ldfrag(&KlL[qrowL][t * 16 + g2 * 4]);
    }
    __syncthreads();

    f32x16 O0, O1;
    #pragma unroll
    for (int i = 0; i < 16; ++i) { O0[i] = 0.f; O1[i] = 0.f; }
    float m = -3.0e38f, lsum = 0.f;

    #pragma unroll
    for (int kt = 0; kt < 2; ++kt) {
        const int k0 = kt * 64;
        stage64(&KhL[0][0], KhB + (size_t)k0 * 64, 64, tid);
        stage64(&KlL[0][0], KlB + (size_t)k0 * 64, 64, tid);
        stage64(&VhL[0][0], VhB + k0, 128, tid);
        stage64(&VlL[0][0], VlB + k0, 128, tid);
        __syncthreads();

        f32x16 s0v, s1v;
        #pragma unroll
        for (int i = 0; i < 16; ++i) { s0v[i] = 0.f; s1v[i] = 0.f; }
        #pragma unroll
        for (int t = 0; t < 4; ++t) {
            const int col = t * 16 + g2 * 4;
            const s8v kh0 = ldfrag(&KhL[l5][col]);
            const s8v kl0 = ldfrag(&KlL[l5][col]);
            s0v = MFMA32(kh0, qh[t], s0v);
            s0v = MFMA32(kh0, ql[t], s0v);
            s0v = MFMA32(kl0, qh[t], s0v);
            const s8v kh1 = ldfrag(&KhL[32 + l5][col]);
            const s8v kl1 = ldfrag(&KlL[32 + l5][col]);
            s1v = MFMA32(kh1, qh[t], s1v);
            s1v = MFMA32(kh1, ql[t], s1v);
            s1v = MFMA32(kl1, qh[t], s1v);
        }

        // mask pad slots (kv = 96 + (i&3)+8*(i>>2)+4*g2 for s1v in kt==1)
        if (kt == 1) {
            #pragma unroll
            for (int i = 0; i < 16; ++i)
                if (g2 == 1 || i >= 4) s1v[i] = -3.0e38f;
        }

        float tmax = s0v[0];
        #pragma unroll
        for (int i = 1; i < 16; ++i) tmax = fmaxf(tmax, s0v[i]);
        #pragma unroll
        for (int i = 0; i < 16; ++i) tmax = fmaxf(tmax, s1v[i]);
        tmax = fmaxf(tmax, __shfl_xor(tmax, 32, 64));
        const float mn = fmaxf(m, tmax);
        const float sc = __expf(m - mn);
        m = mn;
        float rs = 0.f;
        #pragma unroll
        for (int i = 0; i < 16; ++i) { s0v[i] = __expf(s0v[i] - mn); rs += s0v[i]; }
        #pragma unroll
        for (int i = 0; i < 16; ++i) { s1v[i] = __expf(s1v[i] - mn); rs += s1v[i]; }
        rs += __shfl_xor(rs, 32, 64);
        lsum = lsum * sc + rs;
        #pragma unroll
        for (int i = 0; i < 16; ++i) { O0[i] *= sc; O1[i] *= sc; }

        s8v ph[4], pl[4];
        #pragma unroll
        for (int ks = 0; ks < 4; ++ks) {
            const int off = (ks & 1) * 8;
            #pragma unroll
            for (int j = 0; j < 8; ++j) {
                const float f = (ks < 2) ? s0v[off + j] : s1v[off + j];
                const ushortT hi = f2bf(f);
                ph[ks][j] = (short)hi;
                pl[ks][j] = (short)f2bf(f - bf2f(hi));
            }
        }

        #pragma unroll
        for (int ks = 0; ks < 4; ++ks) {
            const int col = ks * 16 + g2 * 4;
            const s8v vh0 = ldfrag(&VhL[l5][col]);
            const s8v vl0 = ldfrag(&VlL[l5][col]);
            O0 = MFMA32(vh0, ph[ks], O0);
            O0 = MFMA32(vh0, pl[ks], O0);
            O0 = MFMA32(vl0, ph[ks], O0);
            const s8v vh1 = ldfrag(&VhL[32 + l5][col]);
            const s8v vl1 = ldfrag(&VlL[32 + l5][col]);
            O1 = MFMA32(vh1, ph[ks], O1);
            O1 = MFMA32(vh1, pl[ks], O1);
            O1 = MFMA32(vl1, ph[ks], O1);
        }
        __syncthreads();
    }

    const float inv = 1.0f / lsum;
    const int grow = b * S_ + q0 + wv * 32 + l5;
    ushortT* hp = cat_hi + (size_t)grow * 1536 + 768 + h * 64;
    ushortT* lp = cat_lo + (size_t)grow * 1536 + 768 + h * 64;
    #pragma unroll
    for (int rb = 0; rb < 4; ++rb) {
        u16x4 h0, l0, h1, l1;
        #pragma unroll
        for (int e = 0; e < 4; ++e) {
            const float f0 = O0[rb * 4 + e] * inv;
            const float f1 = O1[rb * 4 + e] * inv;
            const ushortT i0 = f2bf(f0);
            const ushortT i1 = f2bf(f1);
            h0[e] = i0; l0[e] = f2bf(f0 - bf2f(i0));
            h1[e] = i1; l1[e] = f2bf(f1 - bf2f(i1));
        }
        *(u16x4*)(hp + rb * 8 + g2 * 4)      = h0;
        *(u16x4*)(lp + rb * 8 + g2 * 4)      = l0;
        *(u16x4*)(hp + 32 + rb * 8 + g2 * 4) = h1;
        *(u16x4*)(lp + 32 + rb * 8 + g2 * 4) = l1;
    }
}

// ---------------------------------------------------------------------------
extern "C" void kernel_launch(void* const* d_in, const int* in_sizes, int n_in,
                              void* d_out, int out_size, void* d_ws, size_t ws_size,
                              hipStream_t stream)
{
    const float* x       = (const float*)d_in[0];
    const float* w_attn  = (const float*)d_in[1];
    const float* b_attn  = (const float*)d_in[2];
    const float* w_proj  = (const float*)d_in[3];
    const float* b_proj  = (const float*)d_in[4];
    const float* w_mem   = (const float*)d_in[5];
    const float* b_mem   = (const float*)d_in[6];
    const float* w_alpha = (const float*)d_in[7];
    const float* b_alpha = (const float*)d_in[8];
    const float* memf    = (const float*)d_in[9];
    float* out = (float*)d_out;

    const int B = in_sizes[0] / (S_ * C_);   // 2
    const int BS = B * S_;                   // 4096

    // ---- workspace layout (~90 MB; alias lifetimes in comments) ----
    float* ws   = (float*)d_ws;
    float* qkv  = ws;                                 // [BS][2304] fp32; dies at prep_qkv; slab reused as cat + memKV
    float* mkvb = qkv + (size_t)BS * 2304;            // [100][1536] fp32
    ushortT* u  = (ushortT*)(mkvb + (size_t)M_ * 1536);

    const size_t XS   = (size_t)BS * C_;              // 3,145,728
    const size_t CATS = (size_t)BS * 2 * C_;          // 6,291,456
    const size_t SLAB = (size_t)B * H_ * S_ * 64;     // 3,145,728
    ushortT* x_hi   = u;            ushortT* x_lo   = x_hi + XS;  // x dies at qkv GEMM
    ushortT* wqT_hi = x_lo + XS;    ushortT* wqT_lo = wqT_hi + (size_t)2304 * 768;
    ushortT* waT_hi = wqT_lo + (size_t)2304 * 768;
    ushortT* waT_lo = waT_hi + (size_t)768 * 1536;
    ushortT* wpT_hi = waT_lo + (size_t)768 * 1536;
    ushortT* wpT_lo = wpT_hi + (size_t)768 * 768;
    ushortT* Qh  = wpT_lo + (size_t)768 * 768;
    ushortT* Ql  = Qh + SLAB;
    ushortT* Kh  = Ql + SLAB;
    ushortT* Kl  = Kh + SLAB;
    // aliases:
    //   Vth/Vtl -> dead x slab (written by prep_qkv, read by attn_self)
    //   f_hi/f_lo -> same slab again (written by alpha GEMM after attn_self)
    //   cat + memKV -> dead qkv fp32 slab (25.2 + 0.75 MB inside 37.7 MB)
    ushortT* Vth = x_hi;
    ushortT* Vtl = x_lo;
    ushortT* cat_hi = (ushortT*)qkv;
    ushortT* cat_lo = cat_hi + CATS;
    ushortT* Kmh  = cat_lo + CATS;                    // [12][128][64]
    ushortT* Kml  = Kmh + (size_t)12 * 8192;
    ushortT* Vmth = Kml + (size_t)12 * 8192;          // [12][64][128]
    ushortT* Vmtl = Vmth + (size_t)12 * 8192;
    ushortT* f_hi   = x_hi;
    ushortT* f_lo   = x_lo;

    const dim3 blk(256);

    // weight transpose+split
    prep_wT<<<dim3(2304 / 64, 768 / 64), blk, 0, stream>>>(w_attn, wqT_hi, wqT_lo, 768, 2304);
    prep_wT<<<dim3(768 / 64, 1536 / 64), blk, 0, stream>>>(w_alpha, waT_hi, waT_lo, 1536, 768);
    prep_wT<<<dim3(768 / 64, 768 / 64), blk, 0, stream>>>(w_proj, wpT_hi, wpT_lo, 768, 768);

    // x -> hi/lo bf16
    prep_split<<<dim3((int)(XS / 4 / 256)), blk, 0, stream>>>(x, x_hi, x_lo, (int)(XS / 4));

    // qkv = x @ w_attn + b_attn   (split-bf16 MFMA); x dead after this
    gemm_mfma<0><<<dim3(2304 / 128, BS / 128), blk, 0, stream>>>(
        x_hi, x_lo, wqT_hi, wqT_lo, b_attn, qkv,
        nullptr, nullptr, nullptr, nullptr, BS, 2304, 768);

    // mkv = mem @ w_mem + b_mem   (tiny, fp32)
    gemm64<<<dim3(1536 / 64, 2), blk, 0, stream>>>(memf, w_mem, b_mem, mkvb, M_, 1536, 768);

    // split q/k/v -> hi/lo bf16 (V transposed into dead x slab); qkv fp32 dead after
    prep_qkv<<<dim3(S_ / 64, B * H_), blk, 0, stream>>>(qkv, Qh, Ql, Kh, Kl, Vth, Vtl);

    // memory K/V -> padded hi/lo bf16 (into dead qkv-slab tail; after prep_qkv!)
    prep_mkv<<<dim3(12), blk, 0, stream>>>(mkvb, Kmh, Kml, Vmth, Vmtl);

    // a -> cat[:, 0:768]  (split-bf16 MFMA flash attention)
    attn_self_mfma<<<dim3(S_ / 64, B * H_), dim3(128), 0, stream>>>(
        Qh, Ql, Kh, Kl, Vth, Vtl, cat_hi, cat_lo);

    // a1 -> cat[:, 768:1536]  (split-bf16 MFMA memory attention, 128 padded slots)
    attn_mem_mfma<<<dim3(S_ / 64, B * H_), dim3(128), 0, stream>>>(
        Qh, Ql, Kmh, Kml, Vmth, Vmtl, cat_hi, cat_lo);

    // fused = gate(cat @ w_alpha + b_alpha) -> hi/lo bf16 (into dead V/x slab)
    gemm_mfma<1><<<dim3(768 / 128, BS / 128), blk, 0, stream>>>(
        cat_hi, cat_lo, waT_hi, waT_lo, b_alpha, nullptr,
        cat_hi, cat_lo, f_hi, f_lo, BS, 768, 1536);

    // out = fused @ w_proj + b_proj  (fp32 out)
    gemm_mfma<0><<<dim3(768 / 128, BS / 128), blk, 0, stream>>>(
        f_hi, f_lo, wpT_hi, wpT_lo, b_proj, out,
        nullptr, nullptr, nullptr, nullptr, BS, 768, 768);
}